// Round 4
// baseline (286.005 us; speedup 1.0000x reference)
//
#include <hip/hip_runtime.h>
#include <hip/hip_bf16.h>
#include <cstdint>

// Problem constants
#define TOK   64
#define INF   4096
#define OUTF  11008
#define KCHUNKS 128      // INF / 32
#define NCHB  172        // OUTF / 64 channels per block (grid = 172, no split-K)

using bf16x8  = __attribute__((ext_vector_type(8))) __bf16;
using floatx4 = __attribute__((ext_vector_type(4))) float;

union B8u { uint32_t u[4]; uint4 q; bf16x8 v; };

// pack two fp32 into one dword of two truncated bf16 (elem a = low half)
__device__ __forceinline__ uint32_t hi2(float a, float b) {
    return (__float_as_uint(a) >> 16) | (__float_as_uint(b) & 0xffff0000u);
}
// residual after bf16 truncation (exact in fp32)
__device__ __forceinline__ float losub(float x) {
    return x - __uint_as_float(__float_as_uint(x) & 0xffff0000u);
}
__device__ __forceinline__ void packW(float4 a, float4 b, B8u& wh, B8u& wl) {
    wh.u[0] = hi2(a.x, a.y);  wh.u[1] = hi2(a.z, a.w);
    wh.u[2] = hi2(b.x, b.y);  wh.u[3] = hi2(b.z, b.w);
    wl.u[0] = hi2(losub(a.x), losub(a.y));
    wl.u[1] = hi2(losub(a.z), losub(a.w));
    wl.u[2] = hi2(losub(b.x), losub(b.y));
    wl.u[3] = hi2(losub(b.z), losub(b.w));
}

// ---------------------------------------------------------------------------
// k_prep: MERGED prep_x + lora_t.
//  blocks 0..1023   : fp32 x -> bf16 hi/lo arrays in MFMA A-fragment order.
//  blocks 1024..1279: tm[t][r] = sum_k x[t][k]*A[r][k], one wave per (t,r).
// ---------------------------------------------------------------------------
__global__ __launch_bounds__(256) void k_prep(const float* __restrict__ x,
        const float* __restrict__ A,
        unsigned short* __restrict__ xh, unsigned short* __restrict__ xl,
        float* __restrict__ tm) {
    int b = blockIdx.x;
    if (b < 1024) {
        int idx  = b * 256 + threadIdx.x;                   // 0..262143
        int j    = idx & 7;
        int lane = (idx >> 3) & 63;
        int kc   = (idx >> 9) & 127;
        int mt   = idx >> 16;
        int row  = mt * 16 + (lane & 15);
        int col  = kc * 32 + ((lane >> 4) << 3) + j;
        float v  = x[(size_t)row * INF + col];
        float lo = losub(v);
        xh[idx] = (unsigned short)(__float_as_uint(v) >> 16);
        xl[idx] = (unsigned short)(__float_as_uint(lo) >> 16);
    } else {
        int bb   = b - 1024;                                // 0..255
        int t    = bb & 63;
        int wv   = threadIdx.x >> 6, lane = threadIdx.x & 63;
        int r    = (bb >> 6) * 4 + wv;
        const float4* xr = (const float4*)(x + (size_t)t * INF);
        const float4* ar = (const float4*)(A + (size_t)r * INF);
        float s = 0.f;
#pragma unroll
        for (int i = 0; i < INF / 4 / 64; ++i) {
            float4 a = xr[lane + i * 64], c = ar[lane + i * 64];
            s += a.x * c.x + a.y * c.y + a.z * c.z + a.w * c.w;
        }
#pragma unroll
        for (int off = 32; off > 0; off >>= 1) s += __shfl_down(s, off);
        if (lane == 0) tm[t * 16 + r] = s;
    }
}

// ---------------------------------------------------------------------------
// k_main (R4): NO split-K.  grid = 172 blocks, each owns 64 channels x full
// K=4096 (32 phases of k=128 -- R0's proven DRAM pattern: W rows staged as
// 512B dense segments, rotate-swizzled, 0 bank conflicts).  Exactly ONE
// round of blocks (172 <= 256 CUs): prologue/epilogue bubbles paid once,
// so 1 block/CU costs nothing (R3's failure mode was 5.4 serial rounds).
// Double-buffered 64KB phase slabs (128KB LDS) + counted vmcnt:
//   loop p: s_waitcnt vmcnt(16)  // retire stage(p); stage(p+1) in flight
//           s_barrier; sched_barrier
//           compute(buf p&1)
//           lgkmcnt(0); s_barrier // all waves done reading buf
//           stage(p+2 -> buf)     // queue never drains mid-loop
// Epilogue fused: out = scale*acc + (B[ch]-tm[token]) + bias  -- kills the
// 45MB part round-trip and the k_post launch entirely.
// ---------------------------------------------------------------------------
__global__ __launch_bounds__(256, 1) void k_main(const float* __restrict__ W,
        const uint4* __restrict__ xh, const uint4* __restrict__ xl,
        const float* __restrict__ scale, const float* __restrict__ lB,
        const float* __restrict__ bias, const float* __restrict__ tm,
        float* __restrict__ out) {
    // W slab: rows r=0..63 (channels), granules g=0..31 (16B each, k=128)
    // slot (r,g) holds global k-granule f=(g-r)&31 -> reader uses g=(f+r)&31
    __shared__ uint4 wlds[2][2048];   // 2 x 32 KB
    __shared__ uint4 xsl [2][2048];   // 2 x 32 KB: [hl][mt][kc 0..3][lane]
    __shared__ float tml[1024];       // 4 KB: tm[64][16]

    int tid  = threadIdx.x;
    int lane = tid & 63;
    int wv   = tid >> 6;
    int quad = lane >> 4;
    int nb   = blockIdx.x;
    int chl  = wv * 16 + (lane & 15);    // local channel row (0..63)
    int ch   = nb * 64 + chl;

    int rpar = lane >> 5;                // row parity within a W DMA issue
    int gg   = lane & 31;                // granule within row

    // tm -> LDS FIRST (its auto vmcnt(0) wait happens before any stage issues,
    // so the counted-vmcnt bookkeeping below stays exact).
    ((float4*)tml)[tid] = ((const float4*)tm)[tid];

    floatx4 acc[4] = {};

    auto stage = [&](int p, int bsel) {
        // ---- W slab: 32 issues of 1KB, each = 2 rows x 512B dense ----
#pragma unroll
        for (int t = 0; t < 8; ++t) {
            int i = wv * 8 + t;          // issue 0..31
            int r = i * 2 + rpar;        // row 0..63
            int f = (gg - r) & 31;       // global granule (rotate swizzle)
            const float* src = W + (size_t)(nb * 64 + r) * INF
                             + p * 128 + f * 4;
            __builtin_amdgcn_global_load_lds(
                (const __attribute__((address_space(1))) uint32_t*)src,
                (__attribute__((address_space(3))) uint32_t*)&wlds[bsel][i * 64],
                16, 0, 0);
        }
        // ---- x slab: 32 issues of 1KB, contiguous in frag order ----
#pragma unroll
        for (int t = 0; t < 8; ++t) {
            int j  = wv * 8 + t;         // 0..31: [hl][mt][kc]
            int hl = j >> 4, mt = (j >> 2) & 3, kc = j & 3;
            const uint4* src = (hl ? xl : xh)
                + ((size_t)(mt * KCHUNKS + p * 4 + kc) * 64 + lane);
            __builtin_amdgcn_global_load_lds(
                (const __attribute__((address_space(1))) uint32_t*)src,
                (__attribute__((address_space(3))) uint32_t*)&xsl[bsel][j * 64],
                16, 0, 0);
        }
    };

    auto compute = [&](int buf) {
#pragma unroll
        for (int kc = 0; kc < 4; ++kc) {
            int f0 = (kc * 4 + quad) * 2;
            uint4 wf0 = wlds[buf][chl * 32 + ((f0 + chl) & 31)];
            uint4 wf1 = wlds[buf][chl * 32 + ((f0 + 1 + chl) & 31)];
            B8u wh, wl;
            packW(*(float4*)&wf0, *(float4*)&wf1, wh, wl);
#pragma unroll
            for (int mt = 0; mt < 4; ++mt) {
                B8u ah, al;
                ah.q = xsl[buf][(mt * 4 + kc) * 64 + lane];
                al.q = xsl[buf][(16 + mt * 4 + kc) * 64 + lane];
                acc[mt] = __builtin_amdgcn_mfma_f32_16x16x32_bf16(ah.v, wh.v, acc[mt], 0, 0, 0);
                acc[mt] = __builtin_amdgcn_mfma_f32_16x16x32_bf16(ah.v, wl.v, acc[mt], 0, 0, 0);
                acc[mt] = __builtin_amdgcn_mfma_f32_16x16x32_bf16(al.v, wh.v, acc[mt], 0, 0, 0);
            }
        }
    };

    // prologue: both buffers in flight (32 issues/wave = 128KB/block)
    stage(0, 0);
    stage(1, 1);

#pragma unroll 2
    for (int p = 0; p < 30; ++p) {
        // retire ONLY stage(p); stage(p+1) stays in flight across the barrier
        asm volatile("s_waitcnt vmcnt(16)" ::: "memory");
        __builtin_amdgcn_s_barrier();
        __builtin_amdgcn_sched_barrier(0);   // pin ds_reads below the wait
        const int buf = p & 1;
        compute(buf);
        // all waves done reading buf before its DMA overwrite begins
        asm volatile("s_waitcnt lgkmcnt(0)" ::: "memory");
        __builtin_amdgcn_s_barrier();
        stage(p + 2, buf);
    }
    // p = 30: stage(31) still in flight during this compute
    asm volatile("s_waitcnt vmcnt(16)" ::: "memory");
    __builtin_amdgcn_s_barrier();
    __builtin_amdgcn_sched_barrier(0);
    compute(0);
    // p = 31: final drain
    asm volatile("s_waitcnt vmcnt(0)" ::: "memory");
    __builtin_amdgcn_s_barrier();
    __builtin_amdgcn_sched_barrier(0);
    compute(1);

    // ---- fused epilogue: out = scale*acc + lora(B,tm) + bias ----
    float sc = scale[ch];
    float bs = bias[ch];
    const float4* Br = (const float4*)(lB + (size_t)ch * 16);
    float4 b0 = Br[0], b1 = Br[1], b2 = Br[2], b3 = Br[3];
    // C/D layout (16x16, m89): col = lane&15 (= channel), row = quad*4 + reg (= token)
#pragma unroll
    for (int mt = 0; mt < 4; ++mt) {
#pragma unroll
        for (int r = 0; r < 4; ++r) {
            int token = mt * 16 + quad * 4 + r;
            const float4* tt = (const float4*)&tml[token * 16];
            float4 t0 = tt[0], t1 = tt[1], t2 = tt[2], t3 = tt[3];
            float l = b0.x * t0.x + b0.y * t0.y + b0.z * t0.z + b0.w * t0.w
                    + b1.x * t1.x + b1.y * t1.y + b1.z * t1.z + b1.w * t1.w
                    + b2.x * t2.x + b2.y * t2.y + b2.z * t2.z + b2.w * t2.w
                    + b3.x * t3.x + b3.y * t3.y + b3.z * t3.z + b3.w * t3.w;
            out[(size_t)token * OUTF + ch] = sc * acc[mt][r] + l + bs;
        }
    }
}

extern "C" void kernel_launch(void* const* d_in, const int* in_sizes, int n_in,
                              void* d_out, int out_size, void* d_ws, size_t ws_size,
                              hipStream_t stream) {
    const float* x     = (const float*)d_in[0];
    const float* W     = (const float*)d_in[1];
    const float* scale = (const float*)d_in[2];
    const float* lA    = (const float*)d_in[3];
    const float* lB    = (const float*)d_in[4];
    const float* bias  = (const float*)d_in[5];
    float* out = (float*)d_out;

    char* ws = (char*)d_ws;
    unsigned short* xh = (unsigned short*)(ws);            // 512 KB
    unsigned short* xl = (unsigned short*)(ws + 524288);   // 512 KB
    float* tm   = (float*)(ws + 1048576);                  // 4 KB

    k_prep<<<1280, 256, 0, stream>>>(x, lA, xh, xl, tm);
    k_main<<<NCHB, 256, 0, stream>>>(W, (const uint4*)xh, (const uint4*)xl,
                                     scale, lB, bias, tm, out);
}

// Round 6
// 270.895 us; speedup vs baseline: 1.0558x; 1.0558x over previous
//
#include <hip/hip_runtime.h>
#include <hip/hip_bf16.h>
#include <cstdint>

// Problem constants
#define TOK   64
#define INF   4096
#define OUTF  11008
#define KCHUNKS 128      // INF / 32
#define QCNT  8          // split-K factor -> K_block = 512
#define NCHB  172        // OUTF / 64 channels per block

using bf16x8  = __attribute__((ext_vector_type(8))) __bf16;
using floatx4 = __attribute__((ext_vector_type(4))) float;

union B8u { uint32_t u[4]; uint4 q; bf16x8 v; };

// pack two fp32 into one dword of two truncated bf16 (elem a = low half)
__device__ __forceinline__ uint32_t hi2(float a, float b) {
    return (__float_as_uint(a) >> 16) | (__float_as_uint(b) & 0xffff0000u);
}
// residual after bf16 truncation (exact in fp32)
__device__ __forceinline__ float losub(float x) {
    return x - __uint_as_float(__float_as_uint(x) & 0xffff0000u);
}
__device__ __forceinline__ void packW(float4 a, float4 b, B8u& wh, B8u& wl) {
    wh.u[0] = hi2(a.x, a.y);  wh.u[1] = hi2(a.z, a.w);
    wh.u[2] = hi2(b.x, b.y);  wh.u[3] = hi2(b.z, b.w);
    wl.u[0] = hi2(losub(a.x), losub(a.y));
    wl.u[1] = hi2(losub(a.z), losub(a.w));
    wl.u[2] = hi2(losub(b.x), losub(b.y));
    wl.u[3] = hi2(losub(b.z), losub(b.w));
}

// ---------------------------------------------------------------------------
// k_prep: MERGED prep_x + lora_t (one launch instead of two).
//  blocks 0..1023   : fp32 x -> bf16 hi/lo arrays in MFMA A-fragment order.
//  blocks 1024..1279: tm[t][r] = sum_k x[t][k]*A[r][k], one wave per (t,r).
// ---------------------------------------------------------------------------
__global__ __launch_bounds__(256) void k_prep(const float* __restrict__ x,
        const float* __restrict__ A,
        unsigned short* __restrict__ xh, unsigned short* __restrict__ xl,
        float* __restrict__ tm) {
    int b = blockIdx.x;
    if (b < 1024) {
        int idx  = b * 256 + threadIdx.x;                   // 0..262143
        int j    = idx & 7;
        int lane = (idx >> 3) & 63;
        int kc   = (idx >> 9) & 127;
        int mt   = idx >> 16;
        int row  = mt * 16 + (lane & 15);
        int col  = kc * 32 + ((lane >> 4) << 3) + j;
        float v  = x[(size_t)row * INF + col];
        float lo = losub(v);
        xh[idx] = (unsigned short)(__float_as_uint(v) >> 16);
        xl[idx] = (unsigned short)(__float_as_uint(lo) >> 16);
    } else {
        int bb   = b - 1024;                                // 0..255
        int t    = bb & 63;
        int wv   = threadIdx.x >> 6, lane = threadIdx.x & 63;
        int r    = (bb >> 6) * 4 + wv;
        const float4* xr = (const float4*)(x + (size_t)t * INF);
        const float4* ar = (const float4*)(A + (size_t)r * INF);
        float s = 0.f;
#pragma unroll
        for (int i = 0; i < INF / 4 / 64; ++i) {
            float4 a = xr[lane + i * 64], c = ar[lane + i * 64];
            s += a.x * c.x + a.y * c.y + a.z * c.z + a.w * c.w;
        }
#pragma unroll
        for (int off = 32; off > 0; off >>= 1) s += __shfl_down(s, off);
        if (lane == 0) tm[t * 16 + r] = s;
    }
}

// ---------------------------------------------------------------------------
// k_main (R5 = R0 revert): y = x @ W^T via 16x16x32 bf16 MFMA, fp32 emulated
// hi/lo:  x*w ~= xh*wh + xh*wl + xl*wh
// MEASURED CHAMPION STRUCTURE (275.5 us total).  QCNT=8 split-K, grid=1376,
// 2 blocks/CU (the latency hiding comes from block-level TLP -- R4 proved
// 1 block/CU is latency-death: 113us, all utilizations <8%, duration
// identical for L3-hot and HBM-cold W).  W DMA'd to LDS as 2 rows x 512B
// dense segments, rotate-swizzled (0 bank conflicts).  Simple schedule:
//   sync -> issue 64KB DMA -> sync(drain) -> compute
// Every pipelined variant (R1: 1-barrier prefetch, R2: 4-deep counted
// vmcnt, R3: dbuf 1blk/CU, R4: no-split-K fused) regressed: +5/+11/+8/+10us.
// Do not re-attempt without per-kernel counters proving the bottleneck.
// ---------------------------------------------------------------------------
template<bool ATOMIC>
__global__ __launch_bounds__(256, 2) void k_main(const float* __restrict__ W,
        const uint4* __restrict__ xh, const uint4* __restrict__ xl,
        const float* __restrict__ scale, float* __restrict__ part,
        float* __restrict__ out) {
    // W slab: rows r=0..63 (channels), granules g=0..31 (16B each, k=128)
    // slot (r,g) holds global k-granule f=(g-r)&31 -> reader uses g=(f+r)&31
    __shared__ uint4 wlds[2048];   // 32 KB
    __shared__ uint4 xsl[2048];    // 32 KB: [hl][mt][kc 0..3][lane]

    int tid  = threadIdx.x;
    int lane = tid & 63;
    int wv   = tid >> 6;
    int quad = lane >> 4;
    int nb   = blockIdx.x % NCHB;
    int q    = blockIdx.x / NCHB;        // 0..QCNT-1
    int chl  = wv * 16 + (lane & 15);    // local channel row (0..63)
    int ch   = nb * 64 + chl;

    const int kbase = q * 512;           // starting k (floats) for this block
    int rpar = lane >> 5;                // row parity within a W DMA issue
    int gg   = lane & 31;                // granule within row

    floatx4 acc[4] = {};

    for (int ph = 0; ph < 4; ++ph) {
        __syncthreads();   // previous phase's LDS reads complete before overwrite

        // ---- DMA W slab: 32 issues of 1KB, each = 2 rows x 512B dense ----
#pragma unroll
        for (int t = 0; t < 8; ++t) {
            int i = wv * 8 + t;          // issue 0..31
            int r = i * 2 + rpar;        // row 0..63
            int f = (gg - r) & 31;       // global granule (rotate swizzle)
            const float* src = W + (size_t)(nb * 64 + r) * INF
                             + kbase + ph * 128 + f * 4;
            __builtin_amdgcn_global_load_lds(
                (const __attribute__((address_space(1))) uint32_t*)src,
                (__attribute__((address_space(3))) uint32_t*)&wlds[i * 64],
                16, 0, 0);
        }
        // ---- DMA x slab: 32 issues of 1KB, contiguous in frag order ----
#pragma unroll
        for (int t = 0; t < 8; ++t) {
            int j  = wv * 8 + t;         // 0..31: [hl][mt][kc]
            int hl = j >> 4, mt = (j >> 2) & 3, kc = j & 3;
            const uint4* src = (hl ? xl : xh)
                + ((size_t)(mt * KCHUNKS + q * 16 + ph * 4 + kc) * 64 + lane);
            __builtin_amdgcn_global_load_lds(
                (const __attribute__((address_space(1))) uint32_t*)src,
                (__attribute__((address_space(3))) uint32_t*)&xsl[j * 64],
                16, 0, 0);
        }
        __syncthreads();   // slabs resident

        // ---- compute 4 chunks (k=32 each) ----
#pragma unroll
        for (int kc = 0; kc < 4; ++kc) {
            int f0 = (kc * 4 + quad) * 2;
            uint4 wf0 = wlds[chl * 32 + ((f0 + chl) & 31)];
            uint4 wf1 = wlds[chl * 32 + ((f0 + 1 + chl) & 31)];
            B8u wh, wl;
            packW(*(float4*)&wf0, *(float4*)&wf1, wh, wl);
#pragma unroll
            for (int mt = 0; mt < 4; ++mt) {
                B8u ah, al;
                ah.q = xsl[(mt * 4 + kc) * 64 + lane];
                al.q = xsl[(16 + mt * 4 + kc) * 64 + lane];
                acc[mt] = __builtin_amdgcn_mfma_f32_16x16x32_bf16(ah.v, wh.v, acc[mt], 0, 0, 0);
                acc[mt] = __builtin_amdgcn_mfma_f32_16x16x32_bf16(ah.v, wl.v, acc[mt], 0, 0, 0);
                acc[mt] = __builtin_amdgcn_mfma_f32_16x16x32_bf16(al.v, wh.v, acc[mt], 0, 0, 0);
            }
        }
    }

    // C/D layout (16x16, m89): col = lane&15 (= channel), row = quad*4 + reg (= token)
#pragma unroll
    for (int mt = 0; mt < 4; ++mt) {
        int token = mt * 16 + quad * 4;
#pragma unroll
        for (int r = 0; r < 4; ++r) {
            if constexpr (ATOMIC) {
                atomicAdd(&out[(size_t)(token + r) * OUTF + ch], scale[ch] * acc[mt][r]);
            } else {
                part[((size_t)q * TOK + token + r) * OUTF + ch] = acc[mt][r];
            }
        }
    }
}

// ---------------------------------------------------------------------------
// k_post: out[t][o] = scale[o]*sum_q part[q][t][o] + sum_r tm[t][r]*B[o][r] + bias[o]
// ---------------------------------------------------------------------------
__global__ __launch_bounds__(256) void k_post(const float* __restrict__ part,
        const float* __restrict__ scale, const float* __restrict__ bias,
        const float* __restrict__ lB, const float* __restrict__ tm,
        float* __restrict__ out) {
    int o = blockIdx.x * 256 + threadIdx.x;
    int t = blockIdx.y;
    if (o >= OUTF) return;
    float s = 0.f;
#pragma unroll
    for (int qq = 0; qq < QCNT; ++qq)
        s += part[((size_t)qq * TOK + t) * OUTF + o];
    const float4* Br = (const float4*)(lB + (size_t)o * 16);
    const float4* tr = (const float4*)(tm + (size_t)t * 16);
    float l = 0.f;
#pragma unroll
    for (int i = 0; i < 4; ++i) {
        float4 b = Br[i], tt = tr[i];
        l += b.x * tt.x + b.y * tt.y + b.z * tt.z + b.w * tt.w;
    }
    out[(size_t)t * OUTF + o] = s * scale[o] + l + bias[o];
}

// Fallback pre-init for the atomic path: out = lora + bias, main adds scale*y.
__global__ __launch_bounds__(256) void k_pre(const float* __restrict__ bias,
        const float* __restrict__ lB, const float* __restrict__ tm,
        float* __restrict__ out) {
    int o = blockIdx.x * 256 + threadIdx.x;
    int t = blockIdx.y;
    if (o >= OUTF) return;
    const float4* Br = (const float4*)(lB + (size_t)o * 16);
    const float4* tr = (const float4*)(tm + (size_t)t * 16);
    float l = 0.f;
#pragma unroll
    for (int i = 0; i < 4; ++i) {
        float4 b = Br[i], tt = tr[i];
        l += b.x * tt.x + b.y * tt.y + b.z * tt.z + b.w * tt.w;
    }
    out[(size_t)t * OUTF + o] = l + bias[o];
}

extern "C" void kernel_launch(void* const* d_in, const int* in_sizes, int n_in,
                              void* d_out, int out_size, void* d_ws, size_t ws_size,
                              hipStream_t stream) {
    const float* x     = (const float*)d_in[0];
    const float* W     = (const float*)d_in[1];
    const float* scale = (const float*)d_in[2];
    const float* lA    = (const float*)d_in[3];
    const float* lB    = (const float*)d_in[4];
    const float* bias  = (const float*)d_in[5];
    float* out = (float*)d_out;

    char* ws = (char*)d_ws;
    unsigned short* xh = (unsigned short*)(ws);            // 512 KB
    unsigned short* xl = (unsigned short*)(ws + 524288);   // 512 KB
    float* tm   = (float*)(ws + 1048576);                  // 4 KB
    float* part = (float*)(ws + 1052672);                  // 22.5 MB
    const size_t need = 1052672 + (size_t)QCNT * TOK * OUTF * 4;  // ~23.6 MB

    k_prep<<<1280, 256, 0, stream>>>(x, lA, xh, xl, tm);

    if (ws_size >= need) {
        k_main<false><<<NCHB * QCNT, 256, 0, stream>>>(W, (const uint4*)xh,
                (const uint4*)xl, scale, part, out);
        k_post<<<dim3(43, TOK), 256, 0, stream>>>(part, scale, bias, lB, tm, out);
    } else {
        k_pre<<<dim3(43, TOK), 256, 0, stream>>>(bias, lB, tm, out);
        k_main<true><<<NCHB * QCNT, 256, 0, stream>>>(W, (const uint4*)xh,
                (const uint4*)xl, scale, nullptr, out);
    }
}

// Round 7
// 270.829 us; speedup vs baseline: 1.0560x; 1.0002x over previous
//
#include <hip/hip_runtime.h>
#include <hip/hip_bf16.h>
#include <cstdint>

// Problem constants
#define TOK   64
#define INF   4096
#define OUTF  11008
#define KCHUNKS 128      // INF / 32
#define QCNT  4          // split-K factor -> K_block = 1024 (R7: was 8)
#define NCHB  172        // OUTF / 64 channels per block

using bf16x8  = __attribute__((ext_vector_type(8))) __bf16;
using floatx4 = __attribute__((ext_vector_type(4))) float;

union B8u { uint32_t u[4]; uint4 q; bf16x8 v; };

// pack two fp32 into one dword of two truncated bf16 (elem a = low half)
__device__ __forceinline__ uint32_t hi2(float a, float b) {
    return (__float_as_uint(a) >> 16) | (__float_as_uint(b) & 0xffff0000u);
}
// residual after bf16 truncation (exact in fp32)
__device__ __forceinline__ float losub(float x) {
    return x - __uint_as_float(__float_as_uint(x) & 0xffff0000u);
}
__device__ __forceinline__ void packW(float4 a, float4 b, B8u& wh, B8u& wl) {
    wh.u[0] = hi2(a.x, a.y);  wh.u[1] = hi2(a.z, a.w);
    wh.u[2] = hi2(b.x, b.y);  wh.u[3] = hi2(b.z, b.w);
    wl.u[0] = hi2(losub(a.x), losub(a.y));
    wl.u[1] = hi2(losub(a.z), losub(a.w));
    wl.u[2] = hi2(losub(b.x), losub(b.y));
    wl.u[3] = hi2(losub(b.z), losub(b.w));
}

// ---------------------------------------------------------------------------
// k_prep: MERGED prep_x + lora_t (one launch instead of two).
//  blocks 0..1023   : fp32 x -> bf16 hi/lo arrays in MFMA A-fragment order.
//  blocks 1024..1279: tm[t][r] = sum_k x[t][k]*A[r][k], one wave per (t,r).
// ---------------------------------------------------------------------------
__global__ __launch_bounds__(256) void k_prep(const float* __restrict__ x,
        const float* __restrict__ A,
        unsigned short* __restrict__ xh, unsigned short* __restrict__ xl,
        float* __restrict__ tm) {
    int b = blockIdx.x;
    if (b < 1024) {
        int idx  = b * 256 + threadIdx.x;                   // 0..262143
        int j    = idx & 7;
        int lane = (idx >> 3) & 63;
        int kc   = (idx >> 9) & 127;
        int mt   = idx >> 16;
        int row  = mt * 16 + (lane & 15);
        int col  = kc * 32 + ((lane >> 4) << 3) + j;
        float v  = x[(size_t)row * INF + col];
        float lo = losub(v);
        xh[idx] = (unsigned short)(__float_as_uint(v) >> 16);
        xl[idx] = (unsigned short)(__float_as_uint(lo) >> 16);
    } else {
        int bb   = b - 1024;                                // 0..255
        int t    = bb & 63;
        int wv   = threadIdx.x >> 6, lane = threadIdx.x & 63;
        int r    = (bb >> 6) * 4 + wv;
        const float4* xr = (const float4*)(x + (size_t)t * INF);
        const float4* ar = (const float4*)(A + (size_t)r * INF);
        float s = 0.f;
#pragma unroll
        for (int i = 0; i < INF / 4 / 64; ++i) {
            float4 a = xr[lane + i * 64], c = ar[lane + i * 64];
            s += a.x * c.x + a.y * c.y + a.z * c.z + a.w * c.w;
        }
#pragma unroll
        for (int off = 32; off > 0; off >>= 1) s += __shfl_down(s, off);
        if (lane == 0) tm[t * 16 + r] = s;
    }
}

// ---------------------------------------------------------------------------
// k_main: y = x @ W^T via 16x16x32 bf16 MFMA, fp32 emulated hi/lo:
//   x*w ~= xh*wh + xh*wl + xl*wh
// CHAMPION STRUCTURE (R6: 270.9 us total).  2 blocks/CU (latency hiding is
// block-level TLP -- R4 proved 1 block/CU is latency-death: 113us, all
// utilizations <8%, duration identical for L3-hot and HBM-cold W).
// W DMA'd to LDS as 2 rows x 512B dense segments, rotate-swizzled (0 bank
// conflicts).  Simple schedule: sync -> issue 64KB DMA -> sync -> compute.
// Every pipelined variant (R1: 1-barrier prefetch, R2: 4-deep counted
// vmcnt, R3: dbuf 1blk/CU, R4: no-split-K fused) regressed: +5/+11/+8/+10us.
// R7 delta (parameter-only): QCNT 8->4.  K_block=1024 (8 phases), grid=688
// (still 2.7 rounds/CU with backfill), part round-trip 45->22.5 MB total.
// ---------------------------------------------------------------------------
template<bool ATOMIC>
__global__ __launch_bounds__(256, 2) void k_main(const float* __restrict__ W,
        const uint4* __restrict__ xh, const uint4* __restrict__ xl,
        const float* __restrict__ scale, float* __restrict__ part,
        float* __restrict__ out) {
    // W slab: rows r=0..63 (channels), granules g=0..31 (16B each, k=128)
    // slot (r,g) holds global k-granule f=(g-r)&31 -> reader uses g=(f+r)&31
    __shared__ uint4 wlds[2048];   // 32 KB
    __shared__ uint4 xsl[2048];    // 32 KB: [hl][mt][kc 0..3][lane]

    int tid  = threadIdx.x;
    int lane = tid & 63;
    int wv   = tid >> 6;
    int quad = lane >> 4;
    int nb   = blockIdx.x % NCHB;
    int q    = blockIdx.x / NCHB;        // 0..QCNT-1
    int chl  = wv * 16 + (lane & 15);    // local channel row (0..63)
    int ch   = nb * 64 + chl;

    const int kbase = q * 1024;          // starting k (floats) for this block
    int rpar = lane >> 5;                // row parity within a W DMA issue
    int gg   = lane & 31;                // granule within row

    floatx4 acc[4] = {};

    for (int ph = 0; ph < 8; ++ph) {
        __syncthreads();   // previous phase's LDS reads complete before overwrite

        // ---- DMA W slab: 32 issues of 1KB, each = 2 rows x 512B dense ----
#pragma unroll
        for (int t = 0; t < 8; ++t) {
            int i = wv * 8 + t;          // issue 0..31
            int r = i * 2 + rpar;        // row 0..63
            int f = (gg - r) & 31;       // global granule (rotate swizzle)
            const float* src = W + (size_t)(nb * 64 + r) * INF
                             + kbase + ph * 128 + f * 4;
            __builtin_amdgcn_global_load_lds(
                (const __attribute__((address_space(1))) uint32_t*)src,
                (__attribute__((address_space(3))) uint32_t*)&wlds[i * 64],
                16, 0, 0);
        }
        // ---- DMA x slab: 32 issues of 1KB, contiguous in frag order ----
#pragma unroll
        for (int t = 0; t < 8; ++t) {
            int j  = wv * 8 + t;         // 0..31: [hl][mt][kc]
            int hl = j >> 4, mt = (j >> 2) & 3, kc = j & 3;
            const uint4* src = (hl ? xl : xh)
                + ((size_t)(mt * KCHUNKS + q * 32 + ph * 4 + kc) * 64 + lane);
            __builtin_amdgcn_global_load_lds(
                (const __attribute__((address_space(1))) uint32_t*)src,
                (__attribute__((address_space(3))) uint32_t*)&xsl[j * 64],
                16, 0, 0);
        }
        __syncthreads();   // slabs resident

        // ---- compute 4 chunks (k=32 each) ----
#pragma unroll
        for (int kc = 0; kc < 4; ++kc) {
            int f0 = (kc * 4 + quad) * 2;
            uint4 wf0 = wlds[chl * 32 + ((f0 + chl) & 31)];
            uint4 wf1 = wlds[chl * 32 + ((f0 + 1 + chl) & 31)];
            B8u wh, wl;
            packW(*(float4*)&wf0, *(float4*)&wf1, wh, wl);
#pragma unroll
            for (int mt = 0; mt < 4; ++mt) {
                B8u ah, al;
                ah.q = xsl[(mt * 4 + kc) * 64 + lane];
                al.q = xsl[(16 + mt * 4 + kc) * 64 + lane];
                acc[mt] = __builtin_amdgcn_mfma_f32_16x16x32_bf16(ah.v, wh.v, acc[mt], 0, 0, 0);
                acc[mt] = __builtin_amdgcn_mfma_f32_16x16x32_bf16(ah.v, wl.v, acc[mt], 0, 0, 0);
                acc[mt] = __builtin_amdgcn_mfma_f32_16x16x32_bf16(al.v, wh.v, acc[mt], 0, 0, 0);
            }
        }
    }

    // C/D layout (16x16, m89): col = lane&15 (= channel), row = quad*4 + reg (= token)
#pragma unroll
    for (int mt = 0; mt < 4; ++mt) {
        int token = mt * 16 + quad * 4;
#pragma unroll
        for (int r = 0; r < 4; ++r) {
            if constexpr (ATOMIC) {
                atomicAdd(&out[(size_t)(token + r) * OUTF + ch], scale[ch] * acc[mt][r]);
            } else {
                part[((size_t)q * TOK + token + r) * OUTF + ch] = acc[mt][r];
            }
        }
    }
}

// ---------------------------------------------------------------------------
// k_post: out[t][o] = scale[o]*sum_q part[q][t][o] + sum_r tm[t][r]*B[o][r] + bias[o]
// ---------------------------------------------------------------------------
__global__ __launch_bounds__(256) void k_post(const float* __restrict__ part,
        const float* __restrict__ scale, const float* __restrict__ bias,
        const float* __restrict__ lB, const float* __restrict__ tm,
        float* __restrict__ out) {
    int o = blockIdx.x * 256 + threadIdx.x;
    int t = blockIdx.y;
    if (o >= OUTF) return;
    float s = 0.f;
#pragma unroll
    for (int qq = 0; qq < QCNT; ++qq)
        s += part[((size_t)qq * TOK + t) * OUTF + o];
    const float4* Br = (const float4*)(lB + (size_t)o * 16);
    const float4* tr = (const float4*)(tm + (size_t)t * 16);
    float l = 0.f;
#pragma unroll
    for (int i = 0; i < 4; ++i) {
        float4 b = Br[i], tt = tr[i];
        l += b.x * tt.x + b.y * tt.y + b.z * tt.z + b.w * tt.w;
    }
    out[(size_t)t * OUTF + o] = s * scale[o] + l + bias[o];
}

// Fallback pre-init for the atomic path: out = lora + bias, main adds scale*y.
__global__ __launch_bounds__(256) void k_pre(const float* __restrict__ bias,
        const float* __restrict__ lB, const float* __restrict__ tm,
        float* __restrict__ out) {
    int o = blockIdx.x * 256 + threadIdx.x;
    int t = blockIdx.y;
    if (o >= OUTF) return;
    const float4* Br = (const float4*)(lB + (size_t)o * 16);
    const float4* tr = (const float4*)(tm + (size_t)t * 16);
    float l = 0.f;
#pragma unroll
    for (int i = 0; i < 4; ++i) {
        float4 b = Br[i], tt = tr[i];
        l += b.x * tt.x + b.y * tt.y + b.z * tt.z + b.w * tt.w;
    }
    out[(size_t)t * OUTF + o] = l + bias[o];
}

extern "C" void kernel_launch(void* const* d_in, const int* in_sizes, int n_in,
                              void* d_out, int out_size, void* d_ws, size_t ws_size,
                              hipStream_t stream) {
    const float* x     = (const float*)d_in[0];
    const float* W     = (const float*)d_in[1];
    const float* scale = (const float*)d_in[2];
    const float* lA    = (const float*)d_in[3];
    const float* lB    = (const float*)d_in[4];
    const float* bias  = (const float*)d_in[5];
    float* out = (float*)d_out;

    char* ws = (char*)d_ws;
    unsigned short* xh = (unsigned short*)(ws);            // 512 KB
    unsigned short* xl = (unsigned short*)(ws + 524288);   // 512 KB
    float* tm   = (float*)(ws + 1048576);                  // 4 KB
    float* part = (float*)(ws + 1052672);                  // 11.3 MB
    const size_t need = 1052672 + (size_t)QCNT * TOK * OUTF * 4;  // ~12.3 MB

    k_prep<<<1280, 256, 0, stream>>>(x, lA, xh, xl, tm);

    if (ws_size >= need) {
        k_main<false><<<NCHB * QCNT, 256, 0, stream>>>(W, (const uint4*)xh,
                (const uint4*)xl, scale, part, out);
        k_post<<<dim3(43, TOK), 256, 0, stream>>>(part, scale, bias, lB, tm, out);
    } else {
        k_pre<<<dim3(43, TOK), 256, 0, stream>>>(bias, lB, tm, out);
        k_main<true><<<NCHB * QCNT, 256, 0, stream>>>(W, (const uint4*)xh,
                (const uint4*)xl, scale, nullptr, out);
    }
}